// Round 3
// baseline (7649.177 us; speedup 1.0000x reference)
//
#include <hip/hip_runtime.h>

#define NB 16          // batches
#define NPTS 131072    // points per batch
#define NPOINT 1024
#define HID 192
#define OUTC 384
#define BLKS_PER_B 16
#define THREADS_FPS 1024
#define PTS_PER_T 8
#define TAG_INIT 1023u   // it ranges 0..1022, never 1023
#define SLOT_U64 16      // 128B per slot line

__device__ __forceinline__ unsigned long long shfl_u64(unsigned long long v, int src) {
  unsigned int lo = (unsigned int)v, hi = (unsigned int)(v >> 32);
  lo = __shfl(lo, src, 64);
  hi = __shfl(hi, src, 64);
  return ((unsigned long long)hi << 32) | lo;
}

// ---------------- FPS ----------------
// 16 blocks/batch, 8 pts/thread in registers. Per iteration:
//   update md + thread argmax (float cmp, first-max via ascending k)
//   wave shfl reduce -> wave candidate (key + xyz via uniform-k select + shfl)
//   lane0 writes s_key/s_xyz[parity][wid]; ONE __syncthreads
//   all waves: lanes 0..15 reduce the 16 wave keys -> block winner (+xyz from LDS)
//   wave0 lane0 publishes 4 tagged u64 words {key|tag, x|tag, y|tag, z|tag}
//     into this block's private 128B slot line (relaxed agent atomics)
//   all waves: lanes 0..15 poll one slot line each (4 tagged words), reduce,
//     winner xyz shfl'd from the lane that polled the winning block. No barrier.
// Double-buffered by it&1 (LDS and global); max skew between waves/blocks is 1
// iteration (to reach it+2 every participant must have passed it), so parity
// buffers are never overwritten while readable. Tags self-validate each word.
__global__ __launch_bounds__(1024) void fps_kernel(
    const float* __restrict__ points,
    unsigned long long* __restrict__ slots,   // [NB][2][16][SLOT_U64]
    int* __restrict__ fps_idx)                // [NB][NPOINT], [b][0]=0 pre-set
{
  const int blk = blockIdx.x;
  const int b = blk >> 4;
  const int r = blk & 15;
  const int t = threadIdx.x;
  const int lane = t & 63, wid = t >> 6;
  const float* __restrict__ P = points + (size_t)b * NPTS * 3;
  const int base = r << 13;   // r * 8192

  float px[PTS_PER_T], py[PTS_PER_T], pz[PTS_PER_T], md[PTS_PER_T];
#pragma unroll
  for (int k = 0; k < PTS_PER_T; ++k) {
    int i = base + (k << 10) + t;
    const float* pp = P + (size_t)i * 3;
    px[k] = pp[0]; py[k] = pp[1]; pz[k] = pp[2];
    md[k] = 1e10f;
  }

  float lx = P[0], ly = P[1], lz = P[2];   // first selected index is 0

  __shared__ unsigned long long s_key[2][16];
  __shared__ float s_x[2][16], s_y[2][16], s_z[2][16];

  unsigned long long* slot_b = slots + (size_t)b * 2 * 16 * SLOT_U64;

  for (int it = 0; it < NPOINT - 1; ++it) {
    const int par = it & 1;
    // ---- update + per-thread argmax (strict > keeps smallest k == smallest idx) ----
    float bm = -1.0f; int bk = 0;
#pragma unroll
    for (int k = 0; k < PTS_PER_T; ++k) {
      float dx = px[k] - lx, dy = py[k] - ly, dz = pz[k] - lz;
      // numpy op order, no FMA contraction: (dx*dx + dy*dy) + dz*dz
      float d = __fadd_rn(__fadd_rn(__fmul_rn(dx, dx), __fmul_rn(dy, dy)), __fmul_rn(dz, dz));
      float m = fminf(md[k], d);
      md[k] = m;
      if (m > bm) { bm = m; bk = k; }
    }
    int bi = base + (bk << 10) + t;  // batch-local idx of this thread's candidate
    unsigned long long key = ((unsigned long long)__float_as_uint(bm) << 32)
                           | ((unsigned long long)(unsigned)(NPTS - 1 - bi) << 15);
    // ---- wave reduce (max of (dist, inv_idx)) ----
#pragma unroll
    for (int off = 32; off > 0; off >>= 1) {
      unsigned int lo = (unsigned int)key, hi = (unsigned int)(key >> 32);
      lo = __shfl_down(lo, off, 64);
      hi = __shfl_down(hi, off, 64);
      unsigned long long o = ((unsigned long long)hi << 32) | lo;
      key = o > key ? o : key;
    }
    key = shfl_u64(key, 0);  // broadcast wave winner to all lanes
    {
      int iw = NPTS - 1 - (int)((key >> 15) & 0x1FFFFull);
      int tw = (iw - base) & 1023;
      int kw = (iw - base) >> 10;
      float xc = px[0], yc = py[0], zc = pz[0];
#pragma unroll
      for (int k = 1; k < PTS_PER_T; ++k) {
        bool s = (kw == k);
        xc = s ? px[k] : xc; yc = s ? py[k] : yc; zc = s ? pz[k] : zc;
      }
      float xw = __shfl(xc, tw & 63, 64);
      float yw = __shfl(yc, tw & 63, 64);
      float zw = __shfl(zc, tw & 63, 64);
      if (lane == 0) {
        s_key[par][wid] = key;
        s_x[par][wid] = xw; s_y[par][wid] = yw; s_z[par][wid] = zw;
      }
    }
    __syncthreads();  // the only barrier: s_key writes -> reads
    // ---- block reduce: every wave, lanes 0..15 ----
    unsigned long long bkey = 0ull;
    if (lane < 16) {
      bkey = s_key[par][lane];
#pragma unroll
      for (int off = 8; off > 0; off >>= 1) {
        unsigned int lo = (unsigned int)bkey, hi = (unsigned int)(bkey >> 32);
        lo = __shfl_xor(lo, off, 64);
        hi = __shfl_xor(hi, off, 64);
        unsigned long long o = ((unsigned long long)hi << 32) | lo;
        bkey = o > bkey ? o : bkey;
      }
    }
    bkey = shfl_u64(bkey, 0);
    int ib = NPTS - 1 - (int)((bkey >> 15) & 0x1FFFFull);
    int wb = ((ib - base) & 1023) >> 6;      // winning wave within this block
    unsigned long long* buf = slot_b + (size_t)par * 16 * SLOT_U64;
    if (t == 0) {
      float bx = s_x[par][wb], by = s_y[par][wb], bz = s_z[par][wb];
      unsigned long long tg = (unsigned long long)(unsigned int)it;
      unsigned long long* sl = buf + (size_t)r * SLOT_U64;
      __hip_atomic_store(&sl[1], ((unsigned long long)__float_as_uint(bx) << 32) | tg,
                         __ATOMIC_RELAXED, __HIP_MEMORY_SCOPE_AGENT);
      __hip_atomic_store(&sl[2], ((unsigned long long)__float_as_uint(by) << 32) | tg,
                         __ATOMIC_RELAXED, __HIP_MEMORY_SCOPE_AGENT);
      __hip_atomic_store(&sl[3], ((unsigned long long)__float_as_uint(bz) << 32) | tg,
                         __ATOMIC_RELAXED, __HIP_MEMORY_SCOPE_AGENT);
      __hip_atomic_store(&sl[0], bkey | tg,
                         __ATOMIC_RELAXED, __HIP_MEMORY_SCOPE_AGENT);
    }
    // ---- global poll: every wave, lanes 0..15, one slot line each ----
    unsigned long long g0 = 0ull; float fx = 0.f, fy = 0.f, fz = 0.f;
    if (lane < 16) {
      unsigned long long* sl = buf + (size_t)lane * SLOT_U64;
      unsigned long long g1, g2, g3;
      const unsigned int uit = (unsigned int)it;
      for (;;) {
        g0 = __hip_atomic_load(&sl[0], __ATOMIC_RELAXED, __HIP_MEMORY_SCOPE_AGENT);
        g1 = __hip_atomic_load(&sl[1], __ATOMIC_RELAXED, __HIP_MEMORY_SCOPE_AGENT);
        g2 = __hip_atomic_load(&sl[2], __ATOMIC_RELAXED, __HIP_MEMORY_SCOPE_AGENT);
        g3 = __hip_atomic_load(&sl[3], __ATOMIC_RELAXED, __HIP_MEMORY_SCOPE_AGENT);
        unsigned int bad = (((unsigned int)g0 & 0x3FFu) ^ uit)
                         | (((unsigned int)g1 & 0x3FFu) ^ uit)
                         | (((unsigned int)g2 & 0x3FFu) ^ uit)
                         | (((unsigned int)g3 & 0x3FFu) ^ uit);
        if (!bad) break;
      }
      fx = __uint_as_float((unsigned int)(g1 >> 32));
      fy = __uint_as_float((unsigned int)(g2 >> 32));
      fz = __uint_as_float((unsigned int)(g3 >> 32));
#pragma unroll
      for (int off = 8; off > 0; off >>= 1) {
        unsigned int lo = (unsigned int)g0, hi = (unsigned int)(g0 >> 32);
        lo = __shfl_xor(lo, off, 64);
        hi = __shfl_xor(hi, off, 64);
        unsigned long long o = ((unsigned long long)hi << 32) | lo;
        g0 = o > g0 ? o : g0;
      }
    }
    g0 = shfl_u64(g0, 0);
    int gi = NPTS - 1 - (int)((g0 >> 15) & 0x1FFFFull);
    int gr = gi >> 13;                       // winning block
    lx = __shfl(fx, gr, 64);
    ly = __shfl(fy, gr, 64);
    lz = __shfl(fz, gr, 64);
    if (r == 0 && t == 0) fps_idx[b * NPOINT + it + 1] = gi;
  }
}

// ---------------- init ----------------
__global__ void fps_init_kernel(unsigned long long* __restrict__ slots,
                                int* __restrict__ fps_idx)
{
  int i = blockIdx.x * blockDim.x + threadIdx.x;
  if (i < NB * 2 * 16 * SLOT_U64) slots[i] = (unsigned long long)TAG_INIT;
  if (i < NB) fps_idx[i * NPOINT] = 0;
}

// ---------------- MLP ----------------
// 4 rows (centers) per block, 384 threads. Phase 1: 384 threads compute
// hidden (2 MLPs x 192) with exact GELU into LDS. Phase 2: thread o
// accumulates output column o for 4 rows x 2 MLPs with coalesced w2 reads.
__global__ __launch_bounds__(384) void mlp_kernel(
    const float* __restrict__ points,
    const int* __restrict__ fps_idx,
    const float* __restrict__ w1t, const float* __restrict__ b1t,
    const float* __restrict__ w2t, const float* __restrict__ b2t,
    const float* __restrict__ w1p, const float* __restrict__ b1p,
    const float* __restrict__ w2p, const float* __restrict__ b2p,
    float* __restrict__ out)
{
  __shared__ float s_c[4][3];
  __shared__ float s_h[2][HID][4];
  const int t = threadIdx.x;
  const int m0 = blockIdx.x * 4;
  if (t < 4) {
    int m = m0 + t;
    int b = m >> 10;
    int idx = fps_idx[m];
    const float* p = points + ((size_t)b * NPTS + (size_t)idx) * 3;
    s_c[t][0] = p[0]; s_c[t][1] = p[1]; s_c[t][2] = p[2];
  }
  __syncthreads();
  {
    const int mlp = t / HID;            // 0 = token, 1 = pos
    const int k = t - mlp * HID;
    const float* w1 = mlp ? w1p : w1t;
    const float* b1 = mlp ? b1p : b1t;
    float wa = w1[k], wb = w1[HID + k], wc = w1[2 * HID + k], bb = b1[k];
#pragma unroll
    for (int r = 0; r < 4; ++r) {
      float z = s_c[r][0] * wa + s_c[r][1] * wb + s_c[r][2] * wc + bb;
      float g = 0.5f * z * (1.0f + erff(z * 0.70710678118654752440f));
      s_h[mlp][k][r] = g;
    }
  }
  __syncthreads();
  const int o = t;
  float acct[4] = {0.f, 0.f, 0.f, 0.f};
  float accp[4] = {0.f, 0.f, 0.f, 0.f};
  const float* w2t_o = w2t + o;
  const float* w2p_o = w2p + o;
#pragma unroll 4
  for (int k = 0; k < HID; ++k) {
    float wt = w2t_o[(size_t)k * OUTC];
    float wp = w2p_o[(size_t)k * OUTC];
    float4 ht = *(const float4*)&s_h[0][k][0];
    float4 hp = *(const float4*)&s_h[1][k][0];
    acct[0] = fmaf(ht.x, wt, acct[0]);
    acct[1] = fmaf(ht.y, wt, acct[1]);
    acct[2] = fmaf(ht.z, wt, acct[2]);
    acct[3] = fmaf(ht.w, wt, acct[3]);
    accp[0] = fmaf(hp.x, wp, accp[0]);
    accp[1] = fmaf(hp.y, wp, accp[1]);
    accp[2] = fmaf(hp.z, wp, accp[2]);
    accp[3] = fmaf(hp.w, wp, accp[3]);
  }
  float bt = b2t[o], bp = b2p[o];
  const size_t posoff = (size_t)NB * NPOINT * OUTC;
#pragma unroll
  for (int rr = 0; rr < 4; ++rr) {
    size_t m = (size_t)(m0 + rr);
    out[m * OUTC + o] = acct[rr] + bt;
    out[posoff + m * OUTC + o] = accp[rr] + bp;
  }
}

extern "C" void kernel_launch(void* const* d_in, const int* in_sizes, int n_in,
                              void* d_out, int out_size, void* d_ws, size_t ws_size,
                              hipStream_t stream)
{
  const float* points = (const float*)d_in[0];
  const float* w1t = (const float*)d_in[1];
  const float* b1t = (const float*)d_in[2];
  const float* w2t = (const float*)d_in[3];
  const float* b2t = (const float*)d_in[4];
  const float* w1p = (const float*)d_in[5];
  const float* b1p = (const float*)d_in[6];
  const float* w2p = (const float*)d_in[7];
  const float* b2p = (const float*)d_in[8];
  float* out = (float*)d_out;

  char* ws = (char*)d_ws;
  unsigned long long* slots = (unsigned long long*)(ws + 0);  // 16*2*16*16*8 = 65536 B
  int* fps_idx = (int*)(ws + 65536);                          // 16*1024*4 = 65536 B

  hipLaunchKernelGGL(fps_init_kernel, dim3(32), dim3(256), 0, stream,
                     slots, fps_idx);

  void* args[3];
  args[0] = (void*)&points;
  args[1] = (void*)&slots;
  args[2] = (void*)&fps_idx;
  hipLaunchCooperativeKernel((void*)fps_kernel, dim3(NB * BLKS_PER_B),
                             dim3(THREADS_FPS), args, 0, stream);

  hipLaunchKernelGGL(mlp_kernel, dim3(NB * NPOINT / 4), dim3(384), 0, stream,
                     points, fps_idx, w1t, b1t, w2t, b2t, w1p, b1p, w2p, b2p, out);
}

// Round 5
// 3300.272 us; speedup vs baseline: 2.3177x; 2.3177x over previous
//
#include <hip/hip_runtime.h>

#define NB 16          // batches
#define NPTS 131072    // points per batch
#define NPOINT 1024
#define HID 192
#define OUTC 384
#define BLKS_PER_B 16
#define THREADS_FPS 1024
#define PTS_PER_T 8
#define TAG_INIT 1023u   // it ranges 0..1022, never 1023
#define SLOT_U64 16      // 128B per slot line
#define TAGM 0x3FFu

__device__ __forceinline__ unsigned long long shfl_u64(unsigned long long v, int src) {
  unsigned int lo = (unsigned int)v, hi = (unsigned int)(v >> 32);
  lo = __shfl(lo, src, 64);
  hi = __shfl(hi, src, 64);
  return ((unsigned long long)hi << 32) | lo;
}

__device__ __forceinline__ unsigned long long ald_wg(unsigned long long* p) {
  return __hip_atomic_load(p, __ATOMIC_RELAXED, __HIP_MEMORY_SCOPE_WORKGROUP);
}
__device__ __forceinline__ void ast_wg(unsigned long long* p, unsigned long long v) {
  __hip_atomic_store(p, v, __ATOMIC_RELAXED, __HIP_MEMORY_SCOPE_WORKGROUP);
}

// ---------------- FPS ----------------
// 16 blocks/batch, 8 pts/thread in registers. No __syncthreads in the loop:
// all intra-block sync is tagged-LDS dataflow, all inter-block sync is tagged
// 128B global slot lines (one per writer). Key = dist[63:32]|inv17[31:15]|tag[9:0].
// Per iteration:
//   every wave: update md, wave-reduce key, select candidate xyz in-register,
//     lane0 writes 4 tagged words to s_cand[par][wid]
//   wave 0 lanes 0..15: spin s_cand tags -> block reduce -> lane0 publishes
//     {key,x,y,z} (tagged) to this block's private global line -> poll the 16
//     lines (lane=line) -> reduce -> winner xyz via shfl -> lane0 writes tagged
//     s_win[par] (+ fps_idx if block 0)
//   all waves: spin s_win[par] tags -> next center xyz.
// Parity (it&1) double-buffers s_cand/s_win/slots; max skew between any two
// participants is 1 iteration (to publish it+2 you must have observed every
// tag==it+1, which implies everyone finished consuming it), so parity buffers
// are never overwritten while still readable. Tags self-validate every word.
__global__ __launch_bounds__(1024) void fps_kernel(
    const float* __restrict__ points,
    unsigned long long* __restrict__ slots,   // [NB][2][16][SLOT_U64]
    int* __restrict__ fps_idx)                // [NB][NPOINT], [b][0]=0 pre-set
{
  const int blk = blockIdx.x;
  const int b = blk >> 4;
  const int r = blk & 15;
  const int t = threadIdx.x;
  const int lane = t & 63, wid = t >> 6;
  const float* __restrict__ P = points + (size_t)b * NPTS * 3;
  const int base = r << 13;   // r * 8192

  float px[PTS_PER_T], py[PTS_PER_T], pz[PTS_PER_T], md[PTS_PER_T];
#pragma unroll
  for (int k = 0; k < PTS_PER_T; ++k) {
    int i = base + (k << 10) + t;
    const float* pp = P + (size_t)i * 3;
    px[k] = pp[0]; py[k] = pp[1]; pz[k] = pp[2];
    md[k] = 1e10f;
  }

  float lx = P[0], ly = P[1], lz = P[2];   // first selected index is 0

  __shared__ unsigned long long s_cand[2][16][4];  // {key, x|tag, y|tag, z|tag}
  __shared__ unsigned long long s_win[2][4];       // {x|tag, y|tag, z|tag, pad}

  // init LDS tags (LDS persists across kernels -> could alias a valid tag)
  if (t < 128) ((unsigned long long*)s_cand)[t] = (unsigned long long)TAG_INIT;
  if (t < 8)   ((unsigned long long*)s_win)[t]  = (unsigned long long)TAG_INIT;
  __syncthreads();

  unsigned long long* slot_b = slots + (size_t)b * 2 * 16 * SLOT_U64;

  for (int it = 0; it < NPOINT - 1; ++it) {
    const int par = it & 1;
    const unsigned int uit = (unsigned int)it;
    const unsigned long long tg = (unsigned long long)uit;

    // ---- update + per-thread argmax (strict > keeps smallest k == smallest idx) ----
    float bm = -1.0f; int bk = 0;
#pragma unroll
    for (int k = 0; k < PTS_PER_T; ++k) {
      float dx = px[k] - lx, dy = py[k] - ly, dz = pz[k] - lz;
      // numpy op order, no FMA contraction: (dx*dx + dy*dy) + dz*dz
      float d = __fadd_rn(__fadd_rn(__fmul_rn(dx, dx), __fmul_rn(dy, dy)), __fmul_rn(dz, dz));
      float m = fminf(md[k], d);
      md[k] = m;
      if (m > bm) { bm = m; bk = k; }
    }
    int bi = base + (bk << 10) + t;
    unsigned long long key = ((unsigned long long)__float_as_uint(bm) << 32)
                           | ((unsigned long long)(unsigned)(NPTS - 1 - bi) << 15) | tg;
    // ---- wave reduce (tags equal across lanes, compare == (dist, inv_idx)) ----
#pragma unroll
    for (int off = 32; off > 0; off >>= 1) {
      unsigned int lo = (unsigned int)key, hi = (unsigned int)(key >> 32);
      lo = __shfl_down(lo, off, 64);
      hi = __shfl_down(hi, off, 64);
      unsigned long long o = ((unsigned long long)hi << 32) | lo;
      key = o > key ? o : key;
    }
    key = shfl_u64(key, 0);
    {
      int iw = NPTS - 1 - (int)((key >> 15) & 0x1FFFFull);
      int tw = (iw - base) & 1023;
      int kw = (iw - base) >> 10;
      float xc = px[0], yc = py[0], zc = pz[0];
#pragma unroll
      for (int k = 1; k < PTS_PER_T; ++k) {
        bool s = (kw == k);
        xc = s ? px[k] : xc; yc = s ? py[k] : yc; zc = s ? pz[k] : zc;
      }
      float xw = __shfl(xc, tw & 63, 64);
      float yw = __shfl(yc, tw & 63, 64);
      float zw = __shfl(zc, tw & 63, 64);
      if (lane == 0) {
        ast_wg(&s_cand[par][wid][1], ((unsigned long long)__float_as_uint(xw) << 32) | tg);
        ast_wg(&s_cand[par][wid][2], ((unsigned long long)__float_as_uint(yw) << 32) | tg);
        ast_wg(&s_cand[par][wid][3], ((unsigned long long)__float_as_uint(zw) << 32) | tg);
        ast_wg(&s_cand[par][wid][0], key);
      }
    }

    if (wid == 0) {
      if (lane < 16) {
        // ---- gather 16 wave candidates from LDS (tag spin, no barrier) ----
        unsigned long long c0, c1, c2, c3;
        for (;;) {
          c0 = ald_wg(&s_cand[par][lane][0]);
          c1 = ald_wg(&s_cand[par][lane][1]);
          c2 = ald_wg(&s_cand[par][lane][2]);
          c3 = ald_wg(&s_cand[par][lane][3]);
          unsigned int bad = (((unsigned int)c0 & TAGM) ^ uit)
                           | (((unsigned int)c1 & TAGM) ^ uit)
                           | (((unsigned int)c2 & TAGM) ^ uit)
                           | (((unsigned int)c3 & TAGM) ^ uit);
          if (!bad) break;
        }
        float wx = __uint_as_float((unsigned int)(c1 >> 32));
        float wy = __uint_as_float((unsigned int)(c2 >> 32));
        float wz = __uint_as_float((unsigned int)(c3 >> 32));
        // block reduce over 16 keys
        unsigned long long kk = c0;
#pragma unroll
        for (int off = 8; off > 0; off >>= 1) {
          unsigned int lo = (unsigned int)kk, hi = (unsigned int)(kk >> 32);
          lo = __shfl_xor(lo, off, 64);
          hi = __shfl_xor(hi, off, 64);
          unsigned long long o = ((unsigned long long)hi << 32) | lo;
          kk = o > kk ? o : kk;
        }
        int ib = NPTS - 1 - (int)((kk >> 15) & 0x1FFFFull);
        int wb = ((ib - base) & 1023) >> 6;   // winning wave within this block
        float bx = __shfl(wx, wb, 64);
        float by = __shfl(wy, wb, 64);
        float bz = __shfl(wz, wb, 64);
        unsigned long long* buf = slot_b + (size_t)par * 16 * SLOT_U64;
        if (lane == 0) {
          unsigned long long* sl = buf + (size_t)r * SLOT_U64;
          __hip_atomic_store(&sl[1], ((unsigned long long)__float_as_uint(bx) << 32) | tg,
                             __ATOMIC_RELAXED, __HIP_MEMORY_SCOPE_AGENT);
          __hip_atomic_store(&sl[2], ((unsigned long long)__float_as_uint(by) << 32) | tg,
                             __ATOMIC_RELAXED, __HIP_MEMORY_SCOPE_AGENT);
          __hip_atomic_store(&sl[3], ((unsigned long long)__float_as_uint(bz) << 32) | tg,
                             __ATOMIC_RELAXED, __HIP_MEMORY_SCOPE_AGENT);
          __hip_atomic_store(&sl[0], kk,
                             __ATOMIC_RELAXED, __HIP_MEMORY_SCOPE_AGENT);
        }
        // ---- poll the 16 block lines (lane = line), 4 pipelined tagged loads ----
        unsigned long long* sl = buf + (size_t)lane * SLOT_U64;
        unsigned long long g0, g1, g2, g3;
        for (;;) {
          g0 = __hip_atomic_load(&sl[0], __ATOMIC_RELAXED, __HIP_MEMORY_SCOPE_AGENT);
          g1 = __hip_atomic_load(&sl[1], __ATOMIC_RELAXED, __HIP_MEMORY_SCOPE_AGENT);
          g2 = __hip_atomic_load(&sl[2], __ATOMIC_RELAXED, __HIP_MEMORY_SCOPE_AGENT);
          g3 = __hip_atomic_load(&sl[3], __ATOMIC_RELAXED, __HIP_MEMORY_SCOPE_AGENT);
          unsigned int bad = (((unsigned int)g0 & TAGM) ^ uit)
                           | (((unsigned int)g1 & TAGM) ^ uit)
                           | (((unsigned int)g2 & TAGM) ^ uit)
                           | (((unsigned int)g3 & TAGM) ^ uit);
          if (!bad) break;
        }
        float fx = __uint_as_float((unsigned int)(g1 >> 32));
        float fy = __uint_as_float((unsigned int)(g2 >> 32));
        float fz = __uint_as_float((unsigned int)(g3 >> 32));
#pragma unroll
        for (int off = 8; off > 0; off >>= 1) {
          unsigned int lo = (unsigned int)g0, hi = (unsigned int)(g0 >> 32);
          lo = __shfl_xor(lo, off, 64);
          hi = __shfl_xor(hi, off, 64);
          unsigned long long o = ((unsigned long long)hi << 32) | lo;
          g0 = o > g0 ? o : g0;
        }
        int gi = NPTS - 1 - (int)((g0 >> 15) & 0x1FFFFull);
        int gr = gi >> 13;                    // winning block
        float nx = __shfl(fx, gr, 64);
        float ny = __shfl(fy, gr, 64);
        float nz = __shfl(fz, gr, 64);
        if (lane == 0) {
          ast_wg(&s_win[par][0], ((unsigned long long)__float_as_uint(nx) << 32) | tg);
          ast_wg(&s_win[par][1], ((unsigned long long)__float_as_uint(ny) << 32) | tg);
          ast_wg(&s_win[par][2], ((unsigned long long)__float_as_uint(nz) << 32) | tg);
          if (r == 0) fps_idx[b * NPOINT + it + 1] = gi;
        }
      }
      // wave 0 falls through: its lane0 already wrote s_win, spin hits instantly
    }

    // ---- all waves: obtain winner xyz via tagged LDS spin ----
    {
      unsigned long long w0, w1, w2;
      for (;;) {
        w0 = ald_wg(&s_win[par][0]);
        w1 = ald_wg(&s_win[par][1]);
        w2 = ald_wg(&s_win[par][2]);
        unsigned int bad = (((unsigned int)w0 & TAGM) ^ uit)
                         | (((unsigned int)w1 & TAGM) ^ uit)
                         | (((unsigned int)w2 & TAGM) ^ uit);
        if (!bad) break;
        __builtin_amdgcn_s_sleep(1);   // pace: keep DS pipe clear for wave 0
      }
      lx = __uint_as_float((unsigned int)(w0 >> 32));
      ly = __uint_as_float((unsigned int)(w1 >> 32));
      lz = __uint_as_float((unsigned int)(w2 >> 32));
    }
  }
}

// ---------------- init ----------------
__global__ void fps_init_kernel(unsigned long long* __restrict__ slots,
                                int* __restrict__ fps_idx)
{
  int i = blockIdx.x * blockDim.x + threadIdx.x;
  if (i < NB * 2 * 16 * SLOT_U64) slots[i] = (unsigned long long)TAG_INIT;
  if (i < NB) fps_idx[i * NPOINT] = 0;
}

// ---------------- MLP ----------------
__global__ __launch_bounds__(384) void mlp_kernel(
    const float* __restrict__ points,
    const int* __restrict__ fps_idx,
    const float* __restrict__ w1t, const float* __restrict__ b1t,
    const float* __restrict__ w2t, const float* __restrict__ b2t,
    const float* __restrict__ w1p, const float* __restrict__ b1p,
    const float* __restrict__ w2p, const float* __restrict__ b2p,
    float* __restrict__ out)
{
  __shared__ float s_c[4][3];
  __shared__ float s_h[2][HID][4];
  const int t = threadIdx.x;
  const int m0 = blockIdx.x * 4;
  if (t < 4) {
    int m = m0 + t;
    int b = m >> 10;
    int idx = fps_idx[m];
    const float* p = points + ((size_t)b * NPTS + (size_t)idx) * 3;
    s_c[t][0] = p[0]; s_c[t][1] = p[1]; s_c[t][2] = p[2];
  }
  __syncthreads();
  {
    const int mlp = t / HID;            // 0 = token, 1 = pos
    const int k = t - mlp * HID;
    const float* w1 = mlp ? w1p : w1t;
    const float* b1 = mlp ? b1p : b1t;
    float wa = w1[k], wb = w1[HID + k], wc = w1[2 * HID + k], bb = b1[k];
#pragma unroll
    for (int r = 0; r < 4; ++r) {
      float z = s_c[r][0] * wa + s_c[r][1] * wb + s_c[r][2] * wc + bb;
      float g = 0.5f * z * (1.0f + erff(z * 0.70710678118654752440f));
      s_h[mlp][k][r] = g;
    }
  }
  __syncthreads();
  const int o = t;
  float acct[4] = {0.f, 0.f, 0.f, 0.f};
  float accp[4] = {0.f, 0.f, 0.f, 0.f};
  const float* w2t_o = w2t + o;
  const float* w2p_o = w2p + o;
#pragma unroll 4
  for (int k = 0; k < HID; ++k) {
    float wt = w2t_o[(size_t)k * OUTC];
    float wp = w2p_o[(size_t)k * OUTC];
    float4 ht = *(const float4*)&s_h[0][k][0];
    float4 hp = *(const float4*)&s_h[1][k][0];
    acct[0] = fmaf(ht.x, wt, acct[0]);
    acct[1] = fmaf(ht.y, wt, acct[1]);
    acct[2] = fmaf(ht.z, wt, acct[2]);
    acct[3] = fmaf(ht.w, wt, acct[3]);
    accp[0] = fmaf(hp.x, wp, accp[0]);
    accp[1] = fmaf(hp.y, wp, accp[1]);
    accp[2] = fmaf(hp.z, wp, accp[2]);
    accp[3] = fmaf(hp.w, wp, accp[3]);
  }
  float bt = b2t[o], bp = b2p[o];
  const size_t posoff = (size_t)NB * NPOINT * OUTC;
#pragma unroll
  for (int rr = 0; rr < 4; ++rr) {
    size_t m = (size_t)(m0 + rr);
    out[m * OUTC + o] = acct[rr] + bt;
    out[posoff + m * OUTC + o] = accp[rr] + bp;
  }
}

extern "C" void kernel_launch(void* const* d_in, const int* in_sizes, int n_in,
                              void* d_out, int out_size, void* d_ws, size_t ws_size,
                              hipStream_t stream)
{
  const float* points = (const float*)d_in[0];
  const float* w1t = (const float*)d_in[1];
  const float* b1t = (const float*)d_in[2];
  const float* w2t = (const float*)d_in[3];
  const float* b2t = (const float*)d_in[4];
  const float* w1p = (const float*)d_in[5];
  const float* b1p = (const float*)d_in[6];
  const float* w2p = (const float*)d_in[7];
  const float* b2p = (const float*)d_in[8];
  float* out = (float*)d_out;

  char* ws = (char*)d_ws;
  unsigned long long* slots = (unsigned long long*)(ws + 0);  // 16*2*16*16*8 = 65536 B
  int* fps_idx = (int*)(ws + 65536);                          // 16*1024*4 = 65536 B

  hipLaunchKernelGGL(fps_init_kernel, dim3(32), dim3(256), 0, stream,
                     slots, fps_idx);

  void* args[3];
  args[0] = (void*)&points;
  args[1] = (void*)&slots;
  args[2] = (void*)&fps_idx;
  hipLaunchCooperativeKernel((void*)fps_kernel, dim3(NB * BLKS_PER_B),
                             dim3(THREADS_FPS), args, 0, stream);

  hipLaunchKernelGGL(mlp_kernel, dim3(NB * NPOINT / 4), dim3(384), 0, stream,
                     points, fps_idx, w1t, b1t, w2t, b2t, w1p, b1p, w2p, b2p, out);
}

// Round 6
// 3170.031 us; speedup vs baseline: 2.4130x; 1.0411x over previous
//
#include <hip/hip_runtime.h>

#define NB 16          // batches
#define NPTS 131072    // points per batch
#define NPOINT 1024
#define HID 192
#define OUTC 384
#define BLKS_PER_B 16
#define THREADS_FPS 1024
#define PTS_PER_T 8
#define TAG_INIT 1023u   // it ranges 0..1022, never 1023
#define SLOT_U64 16      // 128B per slot line (one line per writer block)
#define TAGM 0x3FFu

static __device__ __forceinline__ unsigned long long ald_ag(const unsigned long long* p) {
  return __hip_atomic_load(p, __ATOMIC_RELAXED, __HIP_MEMORY_SCOPE_AGENT);
}
static __device__ __forceinline__ void ast_ag(unsigned long long* p, unsigned long long v) {
  __hip_atomic_store(p, v, __ATOMIC_RELAXED, __HIP_MEMORY_SCOPE_AGENT);
}
__device__ __forceinline__ unsigned long long shfl_u64(unsigned long long v, int src) {
  unsigned int lo = (unsigned int)v, hi = (unsigned int)(v >> 32);
  lo = __shfl(lo, src, 64);
  hi = __shfl(hi, src, 64);
  return ((unsigned long long)hi << 32) | lo;
}

// ---------------- FPS ----------------
// Round-2 champion structure (2 barriers/iter, wave0-only global polling),
// plus: per-writer 128B slot lines, single-word tagged poll, xyz side-words
// (loaded once post-detect, tag-checked after the reduce), 2-deep pipelined
// poll probes. Slot line r of batch b, parity p: words {key|tag, x|tag,
// y|tag, z|tag}, key = dist[63:32] | inv17[31:15].
// Skew safety: a block publishes iteration it+2 (same parity as it) only
// after its poll observed ALL 16 tags==it+1, which requires every block to
// have fully consumed iteration it. So parity double-buffering suffices.
__global__ __launch_bounds__(1024) void fps_kernel(
    const float* __restrict__ points,
    unsigned long long* __restrict__ slots,   // [NB][2][16][SLOT_U64]
    int* __restrict__ fps_idx)                // [NB][NPOINT], [b][0]=0 pre-set
{
  const int blk = blockIdx.x;
  const int b = blk >> 4;
  const int r = blk & 15;
  const int t = threadIdx.x;
  const int lane = t & 63, wid = t >> 6;
  const float* __restrict__ P = points + (size_t)b * NPTS * 3;
  const int base = r << 13;   // r * 8192

  float px[PTS_PER_T], py[PTS_PER_T], pz[PTS_PER_T], md[PTS_PER_T];
#pragma unroll
  for (int k = 0; k < PTS_PER_T; ++k) {
    int i = base + (k << 10) + t;
    const float* pp = P + (size_t)i * 3;
    px[k] = pp[0]; py[k] = pp[1]; pz[k] = pp[2];
    md[k] = 1e10f;
  }

  float lx = P[0], ly = P[1], lz = P[2];   // first selected index is 0

  __shared__ unsigned long long s_red[16];
  __shared__ float s_x[16], s_y[16], s_z[16];
  __shared__ float s_w[3];

  unsigned long long* slot_b = slots + (size_t)b * 2 * 16 * SLOT_U64;

  for (int it = 0; it < NPOINT - 1; ++it) {
    const int par = it & 1;
    const unsigned int uit = (unsigned int)it;
    const unsigned long long tg = (unsigned long long)uit;

    // ---- update + per-thread argmax (strict > keeps smallest k == smallest idx) ----
    float bm = -1.0f; int bk = 0;
#pragma unroll
    for (int k = 0; k < PTS_PER_T; ++k) {
      float dx = px[k] - lx, dy = py[k] - ly, dz = pz[k] - lz;
      // numpy op order, no FMA contraction: (dx*dx + dy*dy) + dz*dz
      float d = __fadd_rn(__fadd_rn(__fmul_rn(dx, dx), __fmul_rn(dy, dy)), __fmul_rn(dz, dz));
      float m = fminf(md[k], d);
      md[k] = m;
      if (m > bm) { bm = m; bk = k; }
    }
    int bi = base + (bk << 10) + t;
    unsigned long long key = ((unsigned long long)__float_as_uint(bm) << 32)
                           | ((unsigned long long)(unsigned)(NPTS - 1 - bi) << 15);
    // ---- wave reduce (max of (dist, inv_idx)) ----
#pragma unroll
    for (int off = 32; off > 0; off >>= 1) {
      unsigned int lo = (unsigned int)key, hi = (unsigned int)(key >> 32);
      lo = __shfl_down(lo, off, 64);
      hi = __shfl_down(hi, off, 64);
      unsigned long long o = ((unsigned long long)hi << 32) | lo;
      key = o > key ? o : key;
    }
    key = shfl_u64(key, 0);  // broadcast wave winner
    {
      int iw = NPTS - 1 - (int)((key >> 15) & 0x1FFFFull);
      int tw = (iw - base) & 1023;
      int kw = (iw - base) >> 10;
      float xc = px[0], yc = py[0], zc = pz[0];
#pragma unroll
      for (int k = 1; k < PTS_PER_T; ++k) {
        bool s = (kw == k);
        xc = s ? px[k] : xc; yc = s ? py[k] : yc; zc = s ? pz[k] : zc;
      }
      float xw = __shfl(xc, tw & 63, 64);
      float yw = __shfl(yc, tw & 63, 64);
      float zw = __shfl(zc, tw & 63, 64);
      if (lane == 0) {
        s_red[wid] = key;
        s_x[wid] = xw; s_y[wid] = yw; s_z[wid] = zw;
      }
    }
    __syncthreads();  // barrier 1: candidates visible to wave 0

    if (wid == 0 && lane < 16) {
      // ---- block reduce over 16 wave keys ----
      unsigned long long kk = s_red[lane];
#pragma unroll
      for (int off = 8; off > 0; off >>= 1) {
        unsigned int lo = (unsigned int)kk, hi = (unsigned int)(kk >> 32);
        lo = __shfl_xor(lo, off, 64);
        hi = __shfl_xor(hi, off, 64);
        unsigned long long o = ((unsigned long long)hi << 32) | lo;
        kk = o > kk ? o : kk;
      }
      int ib = NPTS - 1 - (int)((kk >> 15) & 0x1FFFFull);
      int wb = ((ib - base) & 1023) >> 6;   // winning wave within this block
      // ---- publish to this block's private 128B line ----
      if (lane == 0) {
        float bx = s_x[wb], by = s_y[wb], bz = s_z[wb];
        unsigned long long* sl = slot_b + (size_t)(par * 16 + r) * SLOT_U64;
        ast_ag(&sl[1], ((unsigned long long)__float_as_uint(bx) << 32) | tg);
        ast_ag(&sl[2], ((unsigned long long)__float_as_uint(by) << 32) | tg);
        ast_ag(&sl[3], ((unsigned long long)__float_as_uint(bz) << 32) | tg);
        ast_ag(&sl[0], kk | tg);
      }
      // ---- poll line `lane`, word0 only, 2-deep pipelined probes ----
      unsigned long long* pl = slot_b + (size_t)(par * 16 + lane) * SLOT_U64;
      unsigned long long g0;
      for (;;) {
        unsigned long long a0 = ald_ag(&pl[0]);
        unsigned long long a1 = ald_ag(&pl[0]);
        if (((unsigned int)a0 & TAGM) == uit) { g0 = a0; break; }
        if (((unsigned int)a1 & TAGM) == uit) { g0 = a1; break; }
      }
      // issue side-word loads now; check tags AFTER the reduce (overlap)
      unsigned long long h1 = ald_ag(&pl[1]);
      unsigned long long h2 = ald_ag(&pl[2]);
      unsigned long long h3 = ald_ag(&pl[3]);
      // ---- global reduce over the 16 block keys ----
      unsigned long long gg = g0;
#pragma unroll
      for (int off = 8; off > 0; off >>= 1) {
        unsigned int lo = (unsigned int)gg, hi = (unsigned int)(gg >> 32);
        lo = __shfl_xor(lo, off, 64);
        hi = __shfl_xor(hi, off, 64);
        unsigned long long o = ((unsigned long long)hi << 32) | lo;
        gg = o > gg ? o : gg;
      }
      // side-word tag check (rarely retries: words 1-3 were stored first)
      for (;;) {
        unsigned int bad = (((unsigned int)h1 & TAGM) ^ uit)
                         | (((unsigned int)h2 & TAGM) ^ uit)
                         | (((unsigned int)h3 & TAGM) ^ uit);
        if (!bad) break;
        h1 = ald_ag(&pl[1]); h2 = ald_ag(&pl[2]); h3 = ald_ag(&pl[3]);
      }
      float fx = __uint_as_float((unsigned int)(h1 >> 32));
      float fy = __uint_as_float((unsigned int)(h2 >> 32));
      float fz = __uint_as_float((unsigned int)(h3 >> 32));
      int gi = NPTS - 1 - (int)((gg >> 15) & 0x1FFFFull);
      int gr = gi >> 13;                    // winning block
      float nx = __shfl(fx, gr, 64);
      float ny = __shfl(fy, gr, 64);
      float nz = __shfl(fz, gr, 64);
      if (lane == 0) {
        s_w[0] = nx; s_w[1] = ny; s_w[2] = nz;
        if (r == 0) fps_idx[b * NPOINT + it + 1] = gi;
      }
    }
    __syncthreads();  // barrier 2: winner xyz visible to all waves
    lx = s_w[0]; ly = s_w[1]; lz = s_w[2];
  }
}

// ---------------- init ----------------
__global__ void fps_init_kernel(unsigned long long* __restrict__ slots,
                                int* __restrict__ fps_idx)
{
  int i = blockIdx.x * blockDim.x + threadIdx.x;
  if (i < NB * 2 * 16 * SLOT_U64) slots[i] = (unsigned long long)TAG_INIT;
  if (i < NB) fps_idx[i * NPOINT] = 0;
}

// ---------------- MLP ----------------
// 4 rows (centers) per block, 384 threads. Phase 1: 384 threads compute
// hidden (2 MLPs x 192) with exact GELU into LDS. Phase 2: thread o
// accumulates output column o for 4 rows x 2 MLPs with coalesced w2 reads.
__global__ __launch_bounds__(384) void mlp_kernel(
    const float* __restrict__ points,
    const int* __restrict__ fps_idx,
    const float* __restrict__ w1t, const float* __restrict__ b1t,
    const float* __restrict__ w2t, const float* __restrict__ b2t,
    const float* __restrict__ w1p, const float* __restrict__ b1p,
    const float* __restrict__ w2p, const float* __restrict__ b2p,
    float* __restrict__ out)
{
  __shared__ float s_c[4][3];
  __shared__ float s_h[2][HID][4];
  const int t = threadIdx.x;
  const int m0 = blockIdx.x * 4;
  if (t < 4) {
    int m = m0 + t;
    int b = m >> 10;
    int idx = fps_idx[m];
    const float* p = points + ((size_t)b * NPTS + (size_t)idx) * 3;
    s_c[t][0] = p[0]; s_c[t][1] = p[1]; s_c[t][2] = p[2];
  }
  __syncthreads();
  {
    const int mlp = t / HID;            // 0 = token, 1 = pos
    const int k = t - mlp * HID;
    const float* w1 = mlp ? w1p : w1t;
    const float* b1 = mlp ? b1p : b1t;
    float wa = w1[k], wb = w1[HID + k], wc = w1[2 * HID + k], bb = b1[k];
#pragma unroll
    for (int r = 0; r < 4; ++r) {
      float z = s_c[r][0] * wa + s_c[r][1] * wb + s_c[r][2] * wc + bb;
      float g = 0.5f * z * (1.0f + erff(z * 0.70710678118654752440f));
      s_h[mlp][k][r] = g;
    }
  }
  __syncthreads();
  const int o = t;
  float acct[4] = {0.f, 0.f, 0.f, 0.f};
  float accp[4] = {0.f, 0.f, 0.f, 0.f};
  const float* w2t_o = w2t + o;
  const float* w2p_o = w2p + o;
#pragma unroll 4
  for (int k = 0; k < HID; ++k) {
    float wt = w2t_o[(size_t)k * OUTC];
    float wp = w2p_o[(size_t)k * OUTC];
    float4 ht = *(const float4*)&s_h[0][k][0];
    float4 hp = *(const float4*)&s_h[1][k][0];
    acct[0] = fmaf(ht.x, wt, acct[0]);
    acct[1] = fmaf(ht.y, wt, acct[1]);
    acct[2] = fmaf(ht.z, wt, acct[2]);
    acct[3] = fmaf(ht.w, wt, acct[3]);
    accp[0] = fmaf(hp.x, wp, accp[0]);
    accp[1] = fmaf(hp.y, wp, accp[1]);
    accp[2] = fmaf(hp.z, wp, accp[2]);
    accp[3] = fmaf(hp.w, wp, accp[3]);
  }
  float bt = b2t[o], bp = b2p[o];
  const size_t posoff = (size_t)NB * NPOINT * OUTC;
#pragma unroll
  for (int rr = 0; rr < 4; ++rr) {
    size_t m = (size_t)(m0 + rr);
    out[m * OUTC + o] = acct[rr] + bt;
    out[posoff + m * OUTC + o] = accp[rr] + bp;
  }
}

extern "C" void kernel_launch(void* const* d_in, const int* in_sizes, int n_in,
                              void* d_out, int out_size, void* d_ws, size_t ws_size,
                              hipStream_t stream)
{
  const float* points = (const float*)d_in[0];
  const float* w1t = (const float*)d_in[1];
  const float* b1t = (const float*)d_in[2];
  const float* w2t = (const float*)d_in[3];
  const float* b2t = (const float*)d_in[4];
  const float* w1p = (const float*)d_in[5];
  const float* b1p = (const float*)d_in[6];
  const float* w2p = (const float*)d_in[7];
  const float* b2p = (const float*)d_in[8];
  float* out = (float*)d_out;

  char* ws = (char*)d_ws;
  unsigned long long* slots = (unsigned long long*)(ws + 0);  // 16*2*16*16*8 = 65536 B
  int* fps_idx = (int*)(ws + 65536);                          // 16*1024*4 = 65536 B

  hipLaunchKernelGGL(fps_init_kernel, dim3(32), dim3(256), 0, stream,
                     slots, fps_idx);

  void* args[3];
  args[0] = (void*)&points;
  args[1] = (void*)&slots;
  args[2] = (void*)&fps_idx;
  hipLaunchCooperativeKernel((void*)fps_kernel, dim3(NB * BLKS_PER_B),
                             dim3(THREADS_FPS), args, 0, stream);

  hipLaunchKernelGGL(mlp_kernel, dim3(NB * NPOINT / 4), dim3(384), 0, stream,
                     points, fps_idx, w1t, b1t, w2t, b2t, w1p, b1p, w2p, b2p, out);
}

// Round 7
// 3160.022 us; speedup vs baseline: 2.4206x; 1.0032x over previous
//
#include <hip/hip_runtime.h>

#define NB 16          // batches
#define NPTS 131072    // points per batch
#define NPOINT 1024
#define HID 192
#define OUTC 384
#define BLKS_PER_B 16
#define THREADS_FPS 1024
#define PTS_PER_T 8
#define TAG_INIT 1023u   // it ranges 0..1022, never 1023
#define TAGM 0x3FFu

static __device__ __forceinline__ unsigned long long ald_ag(const unsigned long long* p) {
  return __hip_atomic_load(p, __ATOMIC_RELAXED, __HIP_MEMORY_SCOPE_AGENT);
}
static __device__ __forceinline__ void ast_ag(unsigned long long* p, unsigned long long v) {
  __hip_atomic_store(p, v, __ATOMIC_RELAXED, __HIP_MEMORY_SCOPE_AGENT);
}
__device__ __forceinline__ unsigned long long shfl_u64(unsigned long long v, int src) {
  unsigned int lo = (unsigned int)v, hi = (unsigned int)(v >> 32);
  lo = __shfl(lo, src, 64);
  hi = __shfl(hi, src, 64);
  return ((unsigned long long)hi << 32) | lo;
}
__device__ __forceinline__ unsigned long long shflxor_max_u64(unsigned long long v, int off) {
  unsigned int lo = (unsigned int)v, hi = (unsigned int)(v >> 32);
  lo = __shfl_xor(lo, off, 64);
  hi = __shfl_xor(hi, off, 64);
  unsigned long long o = ((unsigned long long)hi << 32) | lo;
  return o > v ? o : v;
}

// ---------------- FPS ----------------
// 16 blocks/batch, 8 pts/thread in registers. Inter-block sync: one 512B
// contiguous region per (batch,parity): word 4r+j = block r's
// {key|tag, x|tag, y|tag, z|tag}, key = dist[63:32] | inv17[31:15].
// Publish = lanes 0-3 of wave0, ONE 32B-contiguous store instruction.
// Poll = wave0's 64 lanes, ONE load instruction covering the whole region
// (4 coalesced 128B transactions); detect all 64 tags == it via ballot;
// winner key AND xyz are already in the probe's registers -> in-register
// reduce + 3 shfls, no P[] reload, no extra RT.
// Skew safety (parity double-buffer): a block overwrites parity-p words with
// it+2 only after it detected ALL tags==it+1, which requires every block to
// have published it+1, which requires them all to have detected (and thus
// consumed, in-register) iteration it.
__global__ __launch_bounds__(1024) void fps_kernel(
    const float* __restrict__ points,
    unsigned long long* __restrict__ slots,   // [NB][2][64]
    int* __restrict__ fps_idx)                // [NB][NPOINT], [b][0]=0 pre-set
{
  const int blk = blockIdx.x;
  const int b = blk >> 4;
  const int r = blk & 15;
  const int t = threadIdx.x;
  const int lane = t & 63, wid = t >> 6;
  const float* __restrict__ P = points + (size_t)b * NPTS * 3;
  const int base = r << 13;   // r * 8192

  float px[PTS_PER_T], py[PTS_PER_T], pz[PTS_PER_T], md[PTS_PER_T];
#pragma unroll
  for (int k = 0; k < PTS_PER_T; ++k) {
    int i = base + (k << 10) + t;
    const float* pp = P + (size_t)i * 3;
    px[k] = pp[0]; py[k] = pp[1]; pz[k] = pp[2];
    md[k] = 1e10f;
  }

  float lx = P[0], ly = P[1], lz = P[2];   // first selected index is 0

  __shared__ unsigned long long s_red[16];
  __shared__ float s_x[16], s_y[16], s_z[16];
  __shared__ float s_w[3];

  unsigned long long* region_b = slots + (size_t)b * 2 * 64;

  for (int it = 0; it < NPOINT - 1; ++it) {
    const int par = it & 1;
    const unsigned int uit = (unsigned int)it;
    const unsigned long long tg = (unsigned long long)uit;

    // ---- update + per-thread argmax (strict > keeps smallest k == smallest idx) ----
    float bm = -1.0f; int bk = 0;
#pragma unroll
    for (int k = 0; k < PTS_PER_T; ++k) {
      float dx = px[k] - lx, dy = py[k] - ly, dz = pz[k] - lz;
      // numpy op order, no FMA contraction: (dx*dx + dy*dy) + dz*dz
      float d = __fadd_rn(__fadd_rn(__fmul_rn(dx, dx), __fmul_rn(dy, dy)), __fmul_rn(dz, dz));
      float m = fminf(md[k], d);
      md[k] = m;
      if (m > bm) { bm = m; bk = k; }
    }
    int bi = base + (bk << 10) + t;
    unsigned long long key = ((unsigned long long)__float_as_uint(bm) << 32)
                           | ((unsigned long long)(unsigned)(NPTS - 1 - bi) << 15);
    // ---- wave reduce (max of (dist, inv_idx)) ----
#pragma unroll
    for (int off = 32; off > 0; off >>= 1) {
      unsigned int lo = (unsigned int)key, hi = (unsigned int)(key >> 32);
      lo = __shfl_down(lo, off, 64);
      hi = __shfl_down(hi, off, 64);
      unsigned long long o = ((unsigned long long)hi << 32) | lo;
      key = o > key ? o : key;
    }
    key = shfl_u64(key, 0);  // broadcast wave winner
    {
      int iw = NPTS - 1 - (int)((key >> 15) & 0x1FFFFull);
      int tw = (iw - base) & 1023;
      int kw = (iw - base) >> 10;
      float xc = px[0], yc = py[0], zc = pz[0];
#pragma unroll
      for (int k = 1; k < PTS_PER_T; ++k) {
        bool s = (kw == k);
        xc = s ? px[k] : xc; yc = s ? py[k] : yc; zc = s ? pz[k] : zc;
      }
      float xw = __shfl(xc, tw & 63, 64);
      float yw = __shfl(yc, tw & 63, 64);
      float zw = __shfl(zc, tw & 63, 64);
      if (lane == 0) {
        s_red[wid] = key;
        s_x[wid] = xw; s_y[wid] = yw; s_z[wid] = zw;
      }
    }
    __syncthreads();  // barrier 1: candidates visible to wave 0

    if (wid == 0) {
      // ---- block reduce over 16 wave keys (lanes 0..15) ----
      unsigned long long kk = 0ull;
      if (lane < 16) {
        kk = s_red[lane];
#pragma unroll
        for (int off = 8; off > 0; off >>= 1) kk = shflxor_max_u64(kk, off);
      }
      kk = shfl_u64(kk, 0);   // block winner key to all 64 lanes
      int ib = NPTS - 1 - (int)((kk >> 15) & 0x1FFFFull);
      int wb = ((ib - base) & 1023) >> 6;   // winning wave within this block
      unsigned long long* reg = region_b + (size_t)par * 64;
      // ---- publish: lanes 0-3, one 32B-contiguous store instruction ----
      if (lane < 4) {
        float cw = (lane == 1) ? s_x[wb] : (lane == 2) ? s_y[wb] : s_z[wb];
        unsigned long long w = (lane == 0)
            ? (kk | tg)
            : (((unsigned long long)__float_as_uint(cw) << 32) | tg);
        ast_ag(&reg[4 * r + lane], w);
      }
      // ---- poll: 64 lanes, one load instruction per probe (4 txns) ----
      unsigned long long* pp = reg + lane;
      unsigned long long pv;
      for (;;) {
        unsigned long long a0 = ald_ag(pp);
        unsigned long long a1 = ald_ag(pp);
        if (__ballot(((unsigned int)a0 & TAGM) == uit) == ~0ull) { pv = a0; break; }
        if (__ballot(((unsigned int)a1 & TAGM) == uit) == ~0ull) { pv = a1; break; }
        __builtin_amdgcn_s_sleep(2);   // pace retries: don't flood the fabric
      }
      // ---- in-register global reduce ----
      unsigned long long k4 = shfl_u64(pv, lane & ~3);  // group key to all 4 lanes
      k4 = shflxor_max_u64(k4, 4);
      k4 = shflxor_max_u64(k4, 8);
      k4 = shflxor_max_u64(k4, 16);
      k4 = shflxor_max_u64(k4, 32);
      int gi = NPTS - 1 - (int)((k4 >> 15) & 0x1FFFFull);
      int gr = gi >> 13;                    // winning block
      float myf = __uint_as_float((unsigned int)(pv >> 32));
      float nx = __shfl(myf, 4 * gr + 1, 64);
      float ny = __shfl(myf, 4 * gr + 2, 64);
      float nz = __shfl(myf, 4 * gr + 3, 64);
      if (lane == 0) {
        s_w[0] = nx; s_w[1] = ny; s_w[2] = nz;
        if (r == 0) fps_idx[b * NPOINT + it + 1] = gi;
      }
    }
    __syncthreads();  // barrier 2: winner xyz visible to all waves
    lx = s_w[0]; ly = s_w[1]; lz = s_w[2];
  }
}

// ---------------- init ----------------
__global__ void fps_init_kernel(unsigned long long* __restrict__ slots,
                                int* __restrict__ fps_idx)
{
  int i = blockIdx.x * blockDim.x + threadIdx.x;
  if (i < NB * 2 * 64) slots[i] = (unsigned long long)TAG_INIT;
  if (i < NB) fps_idx[i * NPOINT] = 0;
}

// ---------------- MLP ----------------
// 4 rows (centers) per block, 384 threads. Phase 1: 384 threads compute
// hidden (2 MLPs x 192) with exact GELU into LDS. Phase 2: thread o
// accumulates output column o for 4 rows x 2 MLPs with coalesced w2 reads.
__global__ __launch_bounds__(384) void mlp_kernel(
    const float* __restrict__ points,
    const int* __restrict__ fps_idx,
    const float* __restrict__ w1t, const float* __restrict__ b1t,
    const float* __restrict__ w2t, const float* __restrict__ b2t,
    const float* __restrict__ w1p, const float* __restrict__ b1p,
    const float* __restrict__ w2p, const float* __restrict__ b2p,
    float* __restrict__ out)
{
  __shared__ float s_c[4][3];
  __shared__ float s_h[2][HID][4];
  const int t = threadIdx.x;
  const int m0 = blockIdx.x * 4;
  if (t < 4) {
    int m = m0 + t;
    int b = m >> 10;
    int idx = fps_idx[m];
    const float* p = points + ((size_t)b * NPTS + (size_t)idx) * 3;
    s_c[t][0] = p[0]; s_c[t][1] = p[1]; s_c[t][2] = p[2];
  }
  __syncthreads();
  {
    const int mlp = t / HID;            // 0 = token, 1 = pos
    const int k = t - mlp * HID;
    const float* w1 = mlp ? w1p : w1t;
    const float* b1 = mlp ? b1p : b1t;
    float wa = w1[k], wb = w1[HID + k], wc = w1[2 * HID + k], bb = b1[k];
#pragma unroll
    for (int r = 0; r < 4; ++r) {
      float z = s_c[r][0] * wa + s_c[r][1] * wb + s_c[r][2] * wc + bb;
      float g = 0.5f * z * (1.0f + erff(z * 0.70710678118654752440f));
      s_h[mlp][k][r] = g;
    }
  }
  __syncthreads();
  const int o = t;
  float acct[4] = {0.f, 0.f, 0.f, 0.f};
  float accp[4] = {0.f, 0.f, 0.f, 0.f};
  const float* w2t_o = w2t + o;
  const float* w2p_o = w2p + o;
#pragma unroll 4
  for (int k = 0; k < HID; ++k) {
    float wt = w2t_o[(size_t)k * OUTC];
    float wp = w2p_o[(size_t)k * OUTC];
    float4 ht = *(const float4*)&s_h[0][k][0];
    float4 hp = *(const float4*)&s_h[1][k][0];
    acct[0] = fmaf(ht.x, wt, acct[0]);
    acct[1] = fmaf(ht.y, wt, acct[1]);
    acct[2] = fmaf(ht.z, wt, acct[2]);
    acct[3] = fmaf(ht.w, wt, acct[3]);
    accp[0] = fmaf(hp.x, wp, accp[0]);
    accp[1] = fmaf(hp.y, wp, accp[1]);
    accp[2] = fmaf(hp.z, wp, accp[2]);
    accp[3] = fmaf(hp.w, wp, accp[3]);
  }
  float bt = b2t[o], bp = b2p[o];
  const size_t posoff = (size_t)NB * NPOINT * OUTC;
#pragma unroll
  for (int rr = 0; rr < 4; ++rr) {
    size_t m = (size_t)(m0 + rr);
    out[m * OUTC + o] = acct[rr] + bt;
    out[posoff + m * OUTC + o] = accp[rr] + bp;
  }
}

extern "C" void kernel_launch(void* const* d_in, const int* in_sizes, int n_in,
                              void* d_out, int out_size, void* d_ws, size_t ws_size,
                              hipStream_t stream)
{
  const float* points = (const float*)d_in[0];
  const float* w1t = (const float*)d_in[1];
  const float* b1t = (const float*)d_in[2];
  const float* w2t = (const float*)d_in[3];
  const float* b2t = (const float*)d_in[4];
  const float* w1p = (const float*)d_in[5];
  const float* b1p = (const float*)d_in[6];
  const float* w2p = (const float*)d_in[7];
  const float* b2p = (const float*)d_in[8];
  float* out = (float*)d_out;

  char* ws = (char*)d_ws;
  unsigned long long* slots = (unsigned long long*)(ws + 0);  // 16*2*64*8 = 16384 B
  int* fps_idx = (int*)(ws + 16384);                          // 16*1024*4 = 65536 B

  hipLaunchKernelGGL(fps_init_kernel, dim3(8), dim3(256), 0, stream,
                     slots, fps_idx);

  void* args[3];
  args[0] = (void*)&points;
  args[1] = (void*)&slots;
  args[2] = (void*)&fps_idx;
  hipLaunchCooperativeKernel((void*)fps_kernel, dim3(NB * BLKS_PER_B),
                             dim3(THREADS_FPS), args, 0, stream);

  hipLaunchKernelGGL(mlp_kernel, dim3(NB * NPOINT / 4), dim3(384), 0, stream,
                     points, fps_idx, w1t, b1t, w2t, b2t, w1p, b1p, w2p, b2p, out);
}

// Round 8
// 2574.556 us; speedup vs baseline: 2.9711x; 1.2274x over previous
//
#include <hip/hip_runtime.h>

#define NB 16          // batches
#define NPTS 131072    // points per batch
#define NPOINT 1024
#define HID 192
#define OUTC 384
#define BLKS_PER_B 16
#define THREADS_FPS 1024
#define PTS_PER_T 8
#define TAG_INIT 1023u   // it ranges 0..1022, never 1023
#define TAGM 0x3FFu

static __device__ __forceinline__ unsigned long long ald_ag(const unsigned long long* p) {
  return __hip_atomic_load(p, __ATOMIC_RELAXED, __HIP_MEMORY_SCOPE_AGENT);
}
static __device__ __forceinline__ void ast_ag(unsigned long long* p, unsigned long long v) {
  __hip_atomic_store(p, v, __ATOMIC_RELAXED, __HIP_MEMORY_SCOPE_AGENT);
}
__device__ __forceinline__ unsigned long long shfl_u64(unsigned long long v, int src) {
  unsigned int lo = (unsigned int)v, hi = (unsigned int)(v >> 32);
  lo = __shfl(lo, src, 64);
  hi = __shfl(hi, src, 64);
  return ((unsigned long long)hi << 32) | lo;
}
__device__ __forceinline__ unsigned long long shflxor_max_u64(unsigned long long v, int off) {
  unsigned int lo = (unsigned int)v, hi = (unsigned int)(v >> 32);
  lo = __shfl_xor(lo, off, 64);
  hi = __shfl_xor(hi, off, 64);
  unsigned long long o = ((unsigned long long)hi << 32) | lo;
  return o > v ? o : v;
}

// ---------------- FPS ----------------
// Round-2 champion topology, micro-optimized handshake.
// Inter-block sync: ONE 128B line per (batch,parity) holding 16 u64 words,
// word r = block r's {dist[63:32] | inv17[31:15] | tag[9:0]}.
// Publish: lane 0 of wave 0 stores word r (relaxed agent scope).
// Poll: lanes 0..15 of wave 0, own word each, per-lane exit, with TWO
// independent probe loads in flight (miss costs ~RT/2 instead of RT).
// Winner xyz: NOT in the protocol — resolved after barrier 2 by a uniform
// P[3*gi] load (L2-resident, ~0.1us), as in round 2.
// Skew safety (parity double-buffer): block A publishes it+2 (same parity
// as it) only after all its 16 poll lanes saw tag==it+1, i.e. every block
// published it+1, which required them all to have consumed it.
__global__ __launch_bounds__(1024) void fps_kernel(
    const float* __restrict__ points,
    unsigned long long* __restrict__ slots,   // [NB][2][16]
    int* __restrict__ fps_idx)                // [NB][NPOINT], [b][0]=0 pre-set
{
  const int blk = blockIdx.x;
  const int b = blk >> 4;
  const int r = blk & 15;
  const int t = threadIdx.x;
  const int lane = t & 63, wid = t >> 6;
  const float* __restrict__ P = points + (size_t)b * NPTS * 3;
  const int base = r << 13;   // r * 8192

  float px[PTS_PER_T], py[PTS_PER_T], pz[PTS_PER_T], md[PTS_PER_T];
#pragma unroll
  for (int k = 0; k < PTS_PER_T; ++k) {
    int i = base + (k << 10) + t;
    const float* pp = P + (size_t)i * 3;
    px[k] = pp[0]; py[k] = pp[1]; pz[k] = pp[2];
    md[k] = 1e10f;
  }

  float lx = P[0], ly = P[1], lz = P[2];   // first selected index is 0

  __shared__ unsigned long long s_red[16];
  __shared__ int s_i;

  unsigned long long* region_b = slots + (size_t)b * 2 * 16;

  for (int it = 0; it < NPOINT - 1; ++it) {
    const int par = it & 1;
    const unsigned int uit = (unsigned int)it;
    const unsigned long long tg = (unsigned long long)uit;

    // ---- update + per-thread argmax (strict > keeps smallest k == smallest idx) ----
    float bm = -1.0f; int bk = 0;
#pragma unroll
    for (int k = 0; k < PTS_PER_T; ++k) {
      float dx = px[k] - lx, dy = py[k] - ly, dz = pz[k] - lz;
      // numpy op order, no FMA contraction: (dx*dx + dy*dy) + dz*dz
      float d = __fadd_rn(__fadd_rn(__fmul_rn(dx, dx), __fmul_rn(dy, dy)), __fmul_rn(dz, dz));
      float m = fminf(md[k], d);
      md[k] = m;
      if (m > bm) { bm = m; bk = k; }
    }
    int bi = base + (bk << 10) + t;
    unsigned long long key = ((unsigned long long)__float_as_uint(bm) << 32)
                           | ((unsigned long long)(unsigned)(NPTS - 1 - bi) << 15);
    // ---- wave reduce (max of (dist, inv_idx)) ----
#pragma unroll
    for (int off = 32; off > 0; off >>= 1) {
      unsigned int lo = (unsigned int)key, hi = (unsigned int)(key >> 32);
      lo = __shfl_down(lo, off, 64);
      hi = __shfl_down(hi, off, 64);
      unsigned long long o = ((unsigned long long)hi << 32) | lo;
      key = o > key ? o : key;
    }
    if (lane == 0) s_red[wid] = key;
    __syncthreads();  // barrier 1: wave candidates visible to wave 0

    if (wid == 0) {
      unsigned long long* reg = region_b + (size_t)par * 16;
      unsigned long long kk = 0ull;
      if (lane < 16) {
        // ---- block reduce over 16 wave keys (xor offsets stay within 0..15) ----
        kk = s_red[lane];
        kk = shflxor_max_u64(kk, 8);
        kk = shflxor_max_u64(kk, 4);
        kk = shflxor_max_u64(kk, 2);
        kk = shflxor_max_u64(kk, 1);
        // ---- publish immediately (lane 0) ----
        if (lane == 0) ast_ag(&reg[r], kk | tg);
        // ---- poll own word, 2-deep pipelined probes, per-lane exit ----
        unsigned long long* pw = reg + lane;
        unsigned long long pv;
        for (;;) {
          unsigned long long a0 = ald_ag(pw);
          unsigned long long a1 = ald_ag(pw);
          if (((unsigned int)a0 & TAGM) == uit) { pv = a0; break; }
          if (((unsigned int)a1 & TAGM) == uit) { pv = a1; break; }
        }
        // ---- global reduce over the 16 block keys ----
        pv = shflxor_max_u64(pv, 8);
        pv = shflxor_max_u64(pv, 4);
        pv = shflxor_max_u64(pv, 2);
        pv = shflxor_max_u64(pv, 1);
        int gi = NPTS - 1 - (int)((pv >> 15) & 0x1FFFFull);
        if (lane == 0) {
          s_i = gi;
          if (r == 0) fps_idx[b * NPOINT + it + 1] = gi;
        }
      }
    }
    __syncthreads();  // barrier 2: winner index visible to all waves
    {
      const float* lp = P + (size_t)s_i * 3;   // uniform address, L2-resident
      lx = lp[0]; ly = lp[1]; lz = lp[2];
    }
  }
}

// ---------------- init ----------------
__global__ void fps_init_kernel(unsigned long long* __restrict__ slots,
                                int* __restrict__ fps_idx)
{
  int i = blockIdx.x * blockDim.x + threadIdx.x;
  if (i < NB * 2 * 16) slots[i] = (unsigned long long)TAG_INIT;
  if (i < NB) fps_idx[i * NPOINT] = 0;
}

// ---------------- MLP ----------------
// 4 rows (centers) per block, 384 threads. Phase 1: 384 threads compute
// hidden (2 MLPs x 192) with exact GELU into LDS. Phase 2: thread o
// accumulates output column o for 4 rows x 2 MLPs with coalesced w2 reads.
__global__ __launch_bounds__(384) void mlp_kernel(
    const float* __restrict__ points,
    const int* __restrict__ fps_idx,
    const float* __restrict__ w1t, const float* __restrict__ b1t,
    const float* __restrict__ w2t, const float* __restrict__ b2t,
    const float* __restrict__ w1p, const float* __restrict__ b1p,
    const float* __restrict__ w2p, const float* __restrict__ b2p,
    float* __restrict__ out)
{
  __shared__ float s_c[4][3];
  __shared__ float s_h[2][HID][4];
  const int t = threadIdx.x;
  const int m0 = blockIdx.x * 4;
  if (t < 4) {
    int m = m0 + t;
    int b = m >> 10;
    int idx = fps_idx[m];
    const float* p = points + ((size_t)b * NPTS + (size_t)idx) * 3;
    s_c[t][0] = p[0]; s_c[t][1] = p[1]; s_c[t][2] = p[2];
  }
  __syncthreads();
  {
    const int mlp = t / HID;            // 0 = token, 1 = pos
    const int k = t - mlp * HID;
    const float* w1 = mlp ? w1p : w1t;
    const float* b1 = mlp ? b1p : b1t;
    float wa = w1[k], wb = w1[HID + k], wc = w1[2 * HID + k], bb = b1[k];
#pragma unroll
    for (int r = 0; r < 4; ++r) {
      float z = s_c[r][0] * wa + s_c[r][1] * wb + s_c[r][2] * wc + bb;
      float g = 0.5f * z * (1.0f + erff(z * 0.70710678118654752440f));
      s_h[mlp][k][r] = g;
    }
  }
  __syncthreads();
  const int o = t;
  float acct[4] = {0.f, 0.f, 0.f, 0.f};
  float accp[4] = {0.f, 0.f, 0.f, 0.f};
  const float* w2t_o = w2t + o;
  const float* w2p_o = w2p + o;
#pragma unroll 4
  for (int k = 0; k < HID; ++k) {
    float wt = w2t_o[(size_t)k * OUTC];
    float wp = w2p_o[(size_t)k * OUTC];
    float4 ht = *(const float4*)&s_h[0][k][0];
    float4 hp = *(const float4*)&s_h[1][k][0];
    acct[0] = fmaf(ht.x, wt, acct[0]);
    acct[1] = fmaf(ht.y, wt, acct[1]);
    acct[2] = fmaf(ht.z, wt, acct[2]);
    acct[3] = fmaf(ht.w, wt, acct[3]);
    accp[0] = fmaf(hp.x, wp, accp[0]);
    accp[1] = fmaf(hp.y, wp, accp[1]);
    accp[2] = fmaf(hp.z, wp, accp[2]);
    accp[3] = fmaf(hp.w, wp, accp[3]);
  }
  float bt = b2t[o], bp = b2p[o];
  const size_t posoff = (size_t)NB * NPOINT * OUTC;
#pragma unroll
  for (int rr = 0; rr < 4; ++rr) {
    size_t m = (size_t)(m0 + rr);
    out[m * OUTC + o] = acct[rr] + bt;
    out[posoff + m * OUTC + o] = accp[rr] + bp;
  }
}

extern "C" void kernel_launch(void* const* d_in, const int* in_sizes, int n_in,
                              void* d_out, int out_size, void* d_ws, size_t ws_size,
                              hipStream_t stream)
{
  const float* points = (const float*)d_in[0];
  const float* w1t = (const float*)d_in[1];
  const float* b1t = (const float*)d_in[2];
  const float* w2t = (const float*)d_in[3];
  const float* b2t = (const float*)d_in[4];
  const float* w1p = (const float*)d_in[5];
  const float* b1p = (const float*)d_in[6];
  const float* w2p = (const float*)d_in[7];
  const float* b2p = (const float*)d_in[8];
  float* out = (float*)d_out;

  char* ws = (char*)d_ws;
  unsigned long long* slots = (unsigned long long*)(ws + 0);  // 16*2*16*8 = 4096 B
  int* fps_idx = (int*)(ws + 4096);                           // 16*1024*4 = 65536 B

  hipLaunchKernelGGL(fps_init_kernel, dim3(2), dim3(256), 0, stream,
                     slots, fps_idx);

  void* args[3];
  args[0] = (void*)&points;
  args[1] = (void*)&slots;
  args[2] = (void*)&fps_idx;
  hipLaunchCooperativeKernel((void*)fps_kernel, dim3(NB * BLKS_PER_B),
                             dim3(THREADS_FPS), args, 0, stream);

  hipLaunchKernelGGL(mlp_kernel, dim3(NB * NPOINT / 4), dim3(384), 0, stream,
                     points, fps_idx, w1t, b1t, w2t, b2t, w1p, b1p, w2p, b2p, out);
}